// Round 1
// baseline (414.023 us; speedup 1.0000x reference)
//
#include <hip/hip_runtime.h>

// LIF forward scan: x [B=32, T=16, C=128, H=32, W=32] fp32 -> spikes, same shape.
// Strictly memory-bound: 256 MiB in + 256 MiB out, ~85 us floor at 6.3 TB/s.
//
// R1 change vs previous version: the 16-deep up-front load batch cost 64 VGPRs
// for xt[] alone (~80 total) -> >64 VGPR band -> only 4 waves/SIMD (m69:
// occupancy halves at vgpr={64,128,256}). Restructured to a rolling 8-deep
// prefetch: load t=0..7, then as each slot is consumed refill it with t+8.
// Peak xt live = 32 VGPR, ~50 total -> 8 waves/SIMD (2x TLP) while keeping
// 8-16 loads in flight per wave. __launch_bounds__(256, 8) enforces the <=64
// VGPR budget so the compiler cannot hoist the refill loads back into a
// 16-deep batch.
//
// A/B decision rule (see journal): if dur_us is unchanged vs 413, the timed
// region is dominated by harness poison fills and the kernel is already at
// the memory roofline -> declare ROOFLINE.

#define LIF_THRESH 0.5f
#define LIF_TAU    0.25f

typedef float f4 __attribute__((ext_vector_type(4)));  // native vec: nt builtins OK

constexpr int T         = 16;
constexpr int CHW       = 128 * 32 * 32;   // 131072
constexpr int VEC_PER_T = CHW / 4;         // 32768 float4 per t-slab (pow2)
constexpr int B         = 32;
constexpr int TOTAL_VEC = B * VEC_PER_T;   // 1,048,576 threads

__global__ __launch_bounds__(256, 8) void lif_fwd_kernel(
    const f4* __restrict__ x, f4* __restrict__ out)
{
    int tid = blockIdx.x * 256 + threadIdx.x;   // grid sized exactly

    int b     = tid >> 15;                 // / VEC_PER_T
    int inner = tid & (VEC_PER_T - 1);

    size_t base = (size_t)b * (T * VEC_PER_T) + inner;
    const f4* xp = x   + base;
    f4*       op = out + base;

    // Prologue: 8 independent loads in flight (32 KiB/wave).
    f4 xt[T / 2];
#pragma unroll
    for (int t = 0; t < T / 2; ++t)
        xt[t] = __builtin_nontemporal_load(&xp[t * VEC_PER_T]);

    float mx = 0.f, my = 0.f, mz = 0.f, mw = 0.f;

    // First half: consume slot t, immediately refill it with t+8 so the
    // second-half loads overlap first-half compute + stores.
#pragma unroll
    for (int t = 0; t < T / 2; ++t) {
        f4 v = xt[t];
        xt[t] = __builtin_nontemporal_load(&xp[(t + T / 2) * VEC_PER_T]);

        f4 s;
        mx = mx * LIF_TAU + v.x;
        bool fx = (mx >= LIF_THRESH); s.x = fx ? 1.f : 0.f; mx = fx ? 0.f : mx;

        my = my * LIF_TAU + v.y;
        bool fy = (my >= LIF_THRESH); s.y = fy ? 1.f : 0.f; my = fy ? 0.f : my;

        mz = mz * LIF_TAU + v.z;
        bool fz = (mz >= LIF_THRESH); s.z = fz ? 1.f : 0.f; mz = fz ? 0.f : mz;

        mw = mw * LIF_TAU + v.w;
        bool fw = (mw >= LIF_THRESH); s.w = fw ? 1.f : 0.f; mw = fw ? 0.f : mw;

        __builtin_nontemporal_store(s, &op[t * VEC_PER_T]);
    }

    // Second half: consume the refilled slots.
#pragma unroll
    for (int t = T / 2; t < T; ++t) {
        f4 v = xt[t - T / 2];

        f4 s;
        mx = mx * LIF_TAU + v.x;
        bool fx = (mx >= LIF_THRESH); s.x = fx ? 1.f : 0.f; mx = fx ? 0.f : mx;

        my = my * LIF_TAU + v.y;
        bool fy = (my >= LIF_THRESH); s.y = fy ? 1.f : 0.f; my = fy ? 0.f : my;

        mz = mz * LIF_TAU + v.z;
        bool fz = (mz >= LIF_THRESH); s.z = fz ? 1.f : 0.f; mz = fz ? 0.f : mz;

        mw = mw * LIF_TAU + v.w;
        bool fw = (mw >= LIF_THRESH); s.w = fw ? 1.f : 0.f; mw = fw ? 0.f : mw;

        __builtin_nontemporal_store(s, &op[t * VEC_PER_T]);
    }
}

extern "C" void kernel_launch(void* const* d_in, const int* in_sizes, int n_in,
                              void* d_out, int out_size, void* d_ws, size_t ws_size,
                              hipStream_t stream) {
    const f4* x = (const f4*)d_in[0];
    f4* out = (f4*)d_out;

    const int block = 256;
    const int grid  = TOTAL_VEC / block;   // 4096

    lif_fwd_kernel<<<grid, block, 0, stream>>>(x, out);
}